// Round 6
// baseline (172.146 us; speedup 1.0000x reference)
//
#include <hip/hip_runtime.h>
#include <math.h>

#define EPSF 1e-8f
#define HW 36864
#define SHALF 4753           // 49*97 stored upper half per corr map

// ws float offsets
#define OFF_INV    0
#define OFF_NORM   48
#define OFF_MAX    144       // [0]=pred max bits, [1]=target max bits
#define OFF_ACC    146       // loss accumulator
#define OFF_CNT3   148       // loss finalize counter
#define OFF_PART   160       // 48*2 per-image sum/sumsq atomic partials
#define OFF_CTR    256       // 48 per-image arrival counters
#define OFF_PARTS  1024      // 768*4753 floats: per-(img,chunk) partial corr
#define OFF_SRED   3651328   // 48*4753 floats: chunk-reduced corr maps
#define OFF_PREP   3879472   // ushort region: 48*36864 centered-bf16 images

// autocorr geometry
#define CY 12                // y0 rows per block; 16 chunks/img; 768 blocks = 3/CU
#define AR 61                // staged A rows (rows >= CY+48 feed only discarded sy>48)
#define APITCH 400           // bytes per A row
#define CPB 720              // bytes per B parity copy (45 chunks x 16B)
#define RB 5824              // bytes per staged B row (8 padded copies)
#define ABYTES (AR*APITCH)   // 24400
#define BBYTES (4*RB)        // 23296 (4 rows, single buffer)
#define LDSB (ABYTES + BBYTES)   // 47696 -> 3 blocks/CU
#define ESTR 272             // epilogue lane stride

#define RSEG 19              // reduce_max segments per (t,j)
#define RCHK 251             // offs per segment (19*251 >= 4753)
#define LOSSB2 38            // loss blocks

typedef short short8 __attribute__((ext_vector_type(8)));
typedef float f32x4 __attribute__((ext_vector_type(4)));

__device__ __forceinline__ unsigned int pk2(float a, float b) {
  union { float f; unsigned int u; } x, y;
  x.f = a; y.f = b;
  unsigned int ra = x.u + 0x7fffu + ((x.u >> 16) & 1u);   // RNE to bf16
  unsigned int rb = y.u + 0x7fffu + ((y.u >> 16) & 1u);
  return (ra >> 16) | (rb & 0xffff0000u);
}

// ---------------- Kernel 1: fused stats + centered-bf16 prep ----------------
__global__ __launch_bounds__(256) void stats_prep(const float* __restrict__ pred,
                                                  const float* __restrict__ target,
                                                  float* __restrict__ ws) {
  int blk = blockIdx.x, tid = threadIdx.x;
  int img = blk >> 2, qtr = blk & 3;
  int t = img / 24, local = img % 24;
  const float* src = (t ? target : pred) + (size_t)local * HW + qtr * 9216;

  const float4* s4 = (const float4*)src;
  float s = 0.f, sq = 0.f;
  for (int i = tid; i < 2304; i += 256) {
    float4 v = s4[i];
    s  += (v.x + v.y) + (v.z + v.w);
    sq += (v.x*v.x + v.y*v.y) + (v.z*v.z + v.w*v.w);
  }
#pragma unroll
  for (int o = 32; o > 0; o >>= 1) { s += __shfl_down(s, o); sq += __shfl_down(sq, o); }
  __shared__ float rs[4], rq[4], bcast[1];
  int lane = tid & 63, wv = tid >> 6;
  if (!lane) { rs[wv] = s; rq[wv] = sq; }
  __syncthreads();
  if (!tid) {
    s  = (rs[0] + rs[1]) + (rs[2] + rs[3]);
    sq = (rq[0] + rq[1]) + (rq[2] + rq[3]);
    atomicAdd(&ws[OFF_PART + 2*img],     s);
    atomicAdd(&ws[OFF_PART + 2*img + 1], sq);
    __threadfence();
    atomicAdd((int*)ws + OFF_CTR + img, 1);
    while (atomicAdd((int*)ws + OFF_CTR + img, 0) < 4) { }
    float S1 = atomicAdd(&ws[OFF_PART + 2*img],     0.f);
    float Q  = atomicAdd(&ws[OFF_PART + 2*img + 1], 0.f);
    float mean = S1 / (float)HW;
    float M2 = fmaxf(Q - S1 * S1 / (float)HW, 0.f);
    float inv = 1.f / (sqrtf(M2 / (float)(HW - 1)) + EPSF);
    bcast[0] = mean;
    if (qtr == 0) {
      ws[OFF_INV  + img] = inv;
      ws[OFF_NORM + img] = sqrtf(M2) * inv;   // sqrt(sum xn^2)
    }
  }
  __syncthreads();
  float mean = bcast[0];
  unsigned short* prep = (unsigned short*)(ws + OFF_PREP) + (size_t)img * HW + qtr * 9216;
  for (int i = tid; i < 2304; i += 256) {
    float4 v = s4[i];
    uint2 d; d.x = pk2(v.x - mean, v.y - mean); d.y = pk2(v.z - mean, v.w - mean);
    *(uint2*)(prep + i * 4) = d;
  }
}

// ---------------- Kernel 2: autocorrelation via bf16 MFMA ----------------
// Block = (img, 12-row y0-chunk). Wave w: ks=w&1 takes row parity, sh=w>>1 takes
// s-half (nt 0..3 or 4..6). acc = 4x4 (or 4x3) f32x4 -> ~140 regs -> 3 blocks/CU,
// 768 blocks resident in ONE generation. No global atomics: plain partial stores.
__global__ __launch_bounds__(256, 3) void autocorr_mfma(float* __restrict__ ws) {
  int blk = blockIdx.x;
  int img = blk >> 4, chunk = blk & 15;
  int Y = chunk * CY;
  const unsigned short* prep = (const unsigned short*)(ws + OFF_PREP) + (size_t)img * HW;
  float inv = ws[OFF_INV + img];
  float scale = inv * inv;

  __shared__ __align__(16) char lds[LDSB];
  char* Al = lds;
  char* Bl = lds + ABYTES;

  int tid = threadIdx.x;
  int w = tid >> 6, lane = tid & 63, c = lane & 15, h = lane >> 4;
  int ks = w & 1, sh = w >> 1;

  // ---- A stage: rows Y..Y+60 (zeros beyond image) ----
  int RV = 192 - Y;
  for (int m = tid; m < AR * 24; m += 256) {
    int r = m / 24, k = m - r * 24;
    short8 v = (short8)(short)0;
    if (r < RV) v = *(const short8*)(prep + (Y + r) * 192 + k * 8);
    *(short8*)(Al + r * APITCH + k * 16) = v;
  }

  // ---- B staging, async split: load(j) to regs early, write after barrier ----
  int srr = tid / 45, sk = tid - srr * 45;     // 180 staging threads
  unsigned short q[15];
  auto stage_load = [&](int jd) {
    if (tid < 180) {
      const unsigned short* srow = prep + (Y + 4 * jd + srr) * 192;
      int e0 = 8 * sk - 112;                   // P[E] = u[x = E-112]
#pragma unroll
      for (int i2 = 0; i2 < 15; i2++) {
        int x = e0 + i2;
        q[i2] = ((unsigned)x < 192u) ? srow[x] : (unsigned short)0;
      }
    }
  };
  auto stage_write = [&]() {
    if (tid < 180) {
      unsigned int D[8], Sh[7];
#pragma unroll
      for (int a2 = 0; a2 < 7; a2++) D[a2] = (unsigned)q[2*a2] | ((unsigned)q[2*a2+1] << 16);
      D[7] = (unsigned)q[14];
#pragma unroll
      for (int b2 = 0; b2 < 7; b2++) Sh[b2] = (D[b2] >> 16) | (D[b2+1] << 16);
      char* base = Bl + srr * RB + sk * 16;
#pragma unroll
      for (int p = 0; p < 8; p++) {
        int pb = (p == 0) ? 16 : ((p & 1) ? 80 : 32);
        int4 v;
        if ((p & 1) == 0) { v.x = (int)D[p/2]; v.y = (int)D[p/2+1]; v.z = (int)D[p/2+2]; v.w = (int)D[p/2+3]; }
        else { v.x = (int)Sh[(p-1)/2]; v.y = (int)Sh[(p-1)/2+1]; v.z = (int)Sh[(p-1)/2+2]; v.w = (int)Sh[(p-1)/2+3]; }
        *(int4*)(base + p * CPB + pb) = v;
      }
    }
  };

  // lane-constant B addressing: copy p = (-c) mod 8, pad-equalized
  int p_l = (8 - (c & 7)) & 7;
  int q_l = (c == 0) ? 0 : ((c <= 8) ? 1 : 2);
  int pad_l = (p_l == 0) ? 16 : ((p_l & 1) ? 80 : 32);
  int LB0 = p_l * CPB + pad_l + 16 * (h - q_l) + 128;   // window wi at LB0 + 32*wi

  f32x4 acc[4][4];
#pragma unroll
  for (int mt = 0; mt < 4; mt++)
#pragma unroll
    for (int nt = 0; nt < 4; nt++) acc[mt][nt] = (f32x4)0.f;

  stage_load(0);
  for (int j = 0; j < 3; ++j) {
    __syncthreads();                  // previous compute done reading B
    stage_write();                    // write row-set j
    __syncthreads();                  // B ready
    if (j < 2) stage_load(j + 1);     // issue next loads; hide under compute

#pragma unroll
    for (int rl = 0; rl < 2; ++rl) {
      int brow = 2 * ks + rl;
      int i = 4 * j + brow;
      const char* pB = Bl + brow * RB + LB0;
      int rb[4];
#pragma unroll
      for (int mt = 0; mt < 4; mt++) {
        int ra = i + 16 * mt + c;
        rb[mt] = (ra > 60 ? 60 : ra) * APITCH + 16 * h;
      }
      short8 Wf[8];
#pragma unroll
      for (int wi = 0; wi < 7; wi++) Wf[wi] = *(const short8*)(pB + 32 * wi);
#pragma unroll
      for (int t = 0; t < 6; t++) {
        short8 Af[4];
#pragma unroll
        for (int mt = 0; mt < 4; mt++) Af[mt] = *(const short8*)(Al + rb[mt] + 64 * t);
        if (sh == 0) {
#pragma unroll
          for (int mt = 0; mt < 4; mt++)
#pragma unroll
            for (int ntl = 0; ntl < 4; ntl++)
              acc[mt][ntl] = __builtin_amdgcn_mfma_f32_16x16x32_bf16(Af[mt], Wf[(2*t+6-ntl) & 7], acc[mt][ntl], 0, 0, 0);
        } else {
#pragma unroll
          for (int mt = 0; mt < 4; mt++)
#pragma unroll
            for (int ntl = 0; ntl < 3; ntl++)
              acc[mt][ntl] = __builtin_amdgcn_mfma_f32_16x16x32_bf16(Af[mt], Wf[(2*t+2-ntl) & 7], acc[mt][ntl], 0, 0, 0);
        }
        if (t < 5) {
          Wf[(2*t+7) & 7] = *(const short8*)(pB + 32 * (2*t+7));
          Wf[(2*t+8) & 7] = *(const short8*)(pB + 32 * (2*t+8));
        }
      }
    }
  }

  // ---- K-combine (ks pairs) via LDS, then plain partial stores ----
  __syncthreads();
  if (ks == 1) {
    char* rg = lds + sh * 17408 + lane * ESTR;
#pragma unroll
    for (int mt = 0; mt < 4; mt++)
#pragma unroll
      for (int nt = 0; nt < 4; nt++) *(f32x4*)(rg + (mt*4+nt)*16) = acc[mt][nt];
  }
  __syncthreads();
  if (ks == 0) {
    const char* rg = lds + sh * 17408 + lane * ESTR;
    float* part = ws + OFF_PARTS + (size_t)(img * 16 + chunk) * SHALF;
    int NTL = (sh == 0) ? 4 : 3;
#pragma unroll
    for (int mt = 0; mt < 4; mt++) {
      for (int ntl = 0; ntl < NTL; ntl++) {
        f32x4 o = *(const f32x4*)(rg + (mt*4+ntl)*16);
        int s = ((sh == 0) ? 16 * ntl : 64 + 16 * ntl) + c;
        if (s <= 96) {
#pragma unroll
          for (int r = 0; r < 4; r++) {
            int sy = 16 * mt + 4 * h + r;
            if (sy <= 48)
              part[sy * 97 + s] = (acc[mt][ntl][r] + o[r]) * scale;
          }
        }
      }
    }
  }
}

// ---------------- Kernel 3: 16-chunk reduce -> Sred + global max ----------------
// Block = (t, j, seg): sums 16 chunks for the 3 channels of batch j (side t),
// stores Sred[img][off], computes 8 i-combos and atomicMaxes the side's max.
__global__ __launch_bounds__(256) void reduce_max(float* __restrict__ ws) {
  int blk = blockIdx.x;
  int tj = blk / RSEG, seg = blk - tj * RSEG;
  int t = tj >> 3, jb = tj & 7;
  int imgbase = t * 24 + jb * 3;
  int tid = threadIdx.x;
  __shared__ float wsh[24];
  if (tid < 24) wsh[tid] = (1.f / 3.f) / (ws[OFF_NORM + t * 24 + tid] + EPSF);
  __syncthreads();
  int off = seg * RCHK + tid;
  bool act = (tid < RCHK) && (off < SHALF);
  float p0 = 0.f, p1 = 0.f, p2 = 0.f;
  if (act) {
    const float* P = ws + OFF_PARTS;
    const float* pa = P + (size_t)((imgbase + 0) * 16) * SHALF + off;
    const float* pb = P + (size_t)((imgbase + 1) * 16) * SHALF + off;
    const float* pc = P + (size_t)((imgbase + 2) * 16) * SHALF + off;
#pragma unroll
    for (int ch = 0; ch < 16; ch++) {
      p0 += pa[ch * SHALF]; p1 += pb[ch * SHALF]; p2 += pc[ch * SHALF];
    }
    float* Sred = ws + OFF_SRED;
    Sred[(size_t)(imgbase + 0) * SHALF + off] = p0;
    Sred[(size_t)(imgbase + 1) * SHALF + off] = p1;
    Sred[(size_t)(imgbase + 2) * SHALF + off] = p2;
  }
  float mx = 0.f;
#pragma unroll
  for (int i = 0; i < 8; i++)
    mx = fmaxf(mx, p0 * wsh[i*3] + p1 * wsh[i*3+1] + p2 * wsh[i*3+2]);
#pragma unroll
  for (int o = 32; o > 0; o >>= 1) mx = fmaxf(mx, __shfl_down(mx, o));
  __shared__ float rp[4];
  int lane = tid & 63, wv = tid >> 6;
  if (!lane) rp[wv] = mx;
  __syncthreads();
  if (!tid) {
    mx = fmaxf(fmaxf(rp[0], rp[1]), fmaxf(rp[2], rp[3]));
    atomicMax((int*)ws + OFF_MAX + t, __float_as_int(mx));   // positive floats
  }
}

// ---------------- Kernel 4: loss over Sred + last-block finalize ----------------
__global__ __launch_bounds__(256) void loss_final(float* __restrict__ ws,
                                                  float* __restrict__ out) {
  __shared__ float wsh[48];
  int tid = threadIdx.x;
  if (tid < 48) wsh[tid] = (1.f / 3.f) / (ws[OFF_NORM + tid] + EPSF);
  __syncthreads();
  float imp = 1.f / (__int_as_float(((const int*)ws)[OFF_MAX])     + EPSF);
  float imt = 1.f / (__int_as_float(((const int*)ws)[OFF_MAX + 1]) + EPSF);
  float acc = 0.f;
  const float* Sred = ws + OFF_SRED;
  for (int idx = blockIdx.x * 256 + tid; idx < 8 * SHALF; idx += LOSSB2 * 256) {
    int jb = idx / SHALF, off = idx - jb * SHALF;
    const float* Pp = Sred + (size_t)(3 * jb) * SHALF + off;
    const float* Tt = Sred + (size_t)(24 + 3 * jb) * SHALF + off;
    float p0 = Pp[0], p1 = Pp[SHALF], p2 = Pp[2 * SHALF];
    float q0 = Tt[0], q1 = Tt[SHALF], q2 = Tt[2 * SHALF];
    float a8 = 0.f;
#pragma unroll
    for (int i = 0; i < 8; i++) {
      float pv = (p0 * wsh[i*3] + p1 * wsh[i*3+1] + p2 * wsh[i*3+2]) * imp;
      float tv = (q0 * wsh[24+i*3] + q1 * wsh[24+i*3+1] + q2 * wsh[24+i*3+2]) * imt;
      a8 += fabsf(pv - tv);
    }
    acc += ((off < 97) ? 1.f : 2.f) * a8;   // sy=0 row once, others mirror x2
  }
#pragma unroll
  for (int o = 32; o > 0; o >>= 1) acc += __shfl_down(acc, o);
  __shared__ float r[4];
  int lane = tid & 63, wv = tid >> 6;
  if (!lane) r[wv] = acc;
  __syncthreads();
  if (!tid) {
    float bs = (r[0] + r[1]) + (r[2] + r[3]);
    atomicAdd(&ws[OFF_ACC], bs);
    __threadfence();
    int old = atomicAdd((int*)ws + OFF_CNT3, 1);
    if (old == LOSSB2 - 1) {
      float total = atomicAdd(&ws[OFF_ACC], 0.f);
      out[0] = total * (1.0f / 602176.0f);   // mean over 8*8*97*97
    }
  }
}

extern "C" void kernel_launch(void* const* d_in, const int* in_sizes, int n_in,
                              void* d_out, int out_size, void* d_ws, size_t ws_size,
                              hipStream_t stream) {
  const float* pred   = (const float*)d_in[0];
  const float* target = (const float*)d_in[1];
  float* ws  = (float*)d_ws;
  float* out = (float*)d_out;

  // zero scalars/counters: floats [144, 304)
  hipMemsetAsync((char*)d_ws + 144 * sizeof(float), 0, 160 * sizeof(float), stream);
  hipLaunchKernelGGL(stats_prep,    dim3(192),       dim3(256), 0, stream, pred, target, ws);
  hipLaunchKernelGGL(autocorr_mfma, dim3(48 * 16),   dim3(256), 0, stream, ws);
  hipLaunchKernelGGL(reduce_max,    dim3(16 * RSEG), dim3(256), 0, stream, ws);
  hipLaunchKernelGGL(loss_final,    dim3(LOSSB2),    dim3(256), 0, stream, ws, out);
}

// Round 7
// 69.430 us; speedup vs baseline: 2.4794x; 2.4794x over previous
//
#include <hip/hip_runtime.h>
#include <math.h>

#define EPSF 1e-8f
#define HW 36864
#define SHALF 4753           // 49*97 stored upper half per corr map

// ws float offsets
#define OFF_INV    0
#define OFF_NORM   48
#define OFF_MAX    144       // [0]=pred max bits, [1]=target max bits
#define OFF_ACC    146       // loss accumulator
#define OFF_CNT3   148       // loss finalize counter
#define OFF_PART   160       // 48*2 per-image sum/sumsq atomic partials
#define OFF_CTR    256       // 48 per-image arrival counters
#define OFF_PARTS  1024      // 768*4753 floats: per-(img,chunk) partial corr
#define OFF_SRED   3651328   // 48*4753 floats: chunk-reduced corr maps
#define OFF_PREP   3879472   // ushort region: 48*36864 centered-bf16 images

// autocorr geometry
#define CY 12                // y0 rows per unit; 16 chunks/img; 768 units
#define AR 61                // staged A rows (rows >= CY+48 feed only discarded sy>48)
#define APITCH 400           // bytes per A row
#define CPB 720              // bytes per B parity copy (45 chunks x 16B)
#define RB 5840              // bytes per staged B row buffer (8 padded copies, +16 slack)
#define ABYTES (AR*APITCH)   // 24400
#define LDSB (ABYTES + 8*RB) // 71120 -> 2 blocks/CU
#define ESTR 272             // epilogue lane stride (17 chunks -> bank-uniform)

#define RSEG 19              // reduce_max segments per (t,j)
#define RCHK 251             // offs per segment (19*251 >= 4753)
#define LOSSB2 38            // loss blocks

typedef short short8 __attribute__((ext_vector_type(8)));
typedef float f32x4 __attribute__((ext_vector_type(4)));

__device__ __forceinline__ unsigned int pk2(float a, float b) {
  union { float f; unsigned int u; } x, y;
  x.f = a; y.f = b;
  unsigned int ra = x.u + 0x7fffu + ((x.u >> 16) & 1u);   // RNE to bf16
  unsigned int rb = y.u + 0x7fffu + ((y.u >> 16) & 1u);
  return (ra >> 16) | (rb & 0xffff0000u);
}

// write one staged B row (8 parity-shifted padded copies) from two aligned chunks
__device__ __forceinline__ void writeB(char* buf, uint4 qA, uint4 qB, int lane) {
  if (lane < 45) {
    unsigned int D[8];
    D[0] = qA.x; D[1] = qA.y; D[2] = qA.z; D[3] = qA.w;
    D[4] = qB.x; D[5] = qB.y; D[6] = qB.z; D[7] = qB.w;
    unsigned int Sh[7];
#pragma unroll
    for (int b2 = 0; b2 < 7; b2++) Sh[b2] = (D[b2] >> 16) | (D[b2+1] << 16);
    char* base = buf + lane * 16;
#pragma unroll
    for (int p = 0; p < 8; p++) {
      int pb = (p == 0) ? 16 : ((p & 1) ? 80 : 32);
      uint4 v;
      if (!(p & 1)) { v.x = D[p/2]; v.y = D[p/2+1]; v.z = D[p/2+2]; v.w = D[p/2+3]; }
      else { v.x = Sh[(p-1)/2]; v.y = Sh[(p-1)/2+1]; v.z = Sh[(p-1)/2+2]; v.w = Sh[(p-1)/2+3]; }
      *((uint4*)(base + p * CPB + pb)) = v;
    }
  }
}

// ---------------- Kernel 1: fused stats + centered-bf16 prep ----------------
__global__ __launch_bounds__(256) void stats_prep(const float* __restrict__ pred,
                                                  const float* __restrict__ target,
                                                  float* __restrict__ ws) {
  int blk = blockIdx.x, tid = threadIdx.x;
  int img = blk >> 2, qtr = blk & 3;
  int t = img / 24, local = img % 24;
  const float* src = (t ? target : pred) + (size_t)local * HW + qtr * 9216;

  const float4* s4 = (const float4*)src;
  float s = 0.f, sq = 0.f;
  for (int i = tid; i < 2304; i += 256) {
    float4 v = s4[i];
    s  += (v.x + v.y) + (v.z + v.w);
    sq += (v.x*v.x + v.y*v.y) + (v.z*v.z + v.w*v.w);
  }
#pragma unroll
  for (int o = 32; o > 0; o >>= 1) { s += __shfl_down(s, o); sq += __shfl_down(sq, o); }
  __shared__ float rs[4], rq[4], bcast[1];
  int lane = tid & 63, wv = tid >> 6;
  if (!lane) { rs[wv] = s; rq[wv] = sq; }
  __syncthreads();
  if (!tid) {
    s  = (rs[0] + rs[1]) + (rs[2] + rs[3]);
    sq = (rq[0] + rq[1]) + (rq[2] + rq[3]);
    atomicAdd(&ws[OFF_PART + 2*img],     s);
    atomicAdd(&ws[OFF_PART + 2*img + 1], sq);
    __threadfence();
    atomicAdd((int*)ws + OFF_CTR + img, 1);
    while (atomicAdd((int*)ws + OFF_CTR + img, 0) < 4) { }
    float S1 = atomicAdd(&ws[OFF_PART + 2*img],     0.f);
    float Q  = atomicAdd(&ws[OFF_PART + 2*img + 1], 0.f);
    float mean = S1 / (float)HW;
    float M2 = fmaxf(Q - S1 * S1 / (float)HW, 0.f);
    float inv = 1.f / (sqrtf(M2 / (float)(HW - 1)) + EPSF);
    bcast[0] = mean;
    if (qtr == 0) {
      ws[OFF_INV  + img] = inv;
      ws[OFF_NORM + img] = sqrtf(M2) * inv;   // sqrt(sum xn^2)
    }
  }
  __syncthreads();
  float mean = bcast[0];
  unsigned short* prep = (unsigned short*)(ws + OFF_PREP) + (size_t)img * HW + qtr * 9216;
  for (int i = tid; i < 2304; i += 256) {
    float4 v = s4[i];
    uint2 d; d.x = pk2(v.x - mean, v.y - mean); d.y = pk2(v.z - mean, v.w - mean);
    *(uint2*)(prep + i * 4) = d;
  }
}

// ---------------- Kernel 2: autocorrelation via bf16 MFMA ----------------
// Persistent grid 512; block b does units b and b+512 (b<256) -> 3 units/CU.
// Per unit: one A-stage barrier, then each wave runs rows {w,4+w,8+w} fully
// independently with a wave-private double-buffered B region (no block barriers
// in the K loop; same-wave lgkmcnt orders ds_write->ds_read). acc[4][7] f32x4.
__global__ __launch_bounds__(256, 2) void autocorr_mfma(float* __restrict__ ws) {
  __shared__ __align__(16) char lds[LDSB];
  char* Al = lds;
  char* Bl = lds + ABYTES;

  int tid = threadIdx.x;
  int w = tid >> 6, lane = tid & 63, c = lane & 15, h = lane >> 4;

  // lane-constant B addressing: copy p = (-c) mod 8, pad-equalized
  int p_l = (8 - (c & 7)) & 7;
  int q_l = (c == 0) ? 0 : ((c <= 8) ? 1 : 2);
  int pad_l = (p_l == 0) ? 16 : ((p_l & 1) ? 80 : 32);
  int LB0 = p_l * CPB + pad_l + 16 * (h - q_l) + 128;   // window wi at LB0 + 32*wi

  char* myB = Bl + w * (2 * RB);

  for (int unit = blockIdx.x; unit < 768; unit += 512) {
    int img = unit >> 4, chunk = unit & 15;
    int Y = chunk * CY;
    const unsigned short* prep = (const unsigned short*)(ws + OFF_PREP) + (size_t)img * HW;
    float inv = ws[OFF_INV + img];
    float scale = inv * inv;

    __syncthreads();   // prior unit's epilogue LDS reads complete

    // wave-private B prologue loads (chunks are fully in- or out-of-range)
    uint4 qA, qB;
    qA.x = qA.y = qA.z = qA.w = 0u; qB.x = qB.y = qB.z = qB.w = 0u;
    {
      const char* rowp = (const char*)(prep + (Y + w) * 192) + lane * 16 - 224;
      if (lane >= 14 && lane <= 37) qA = *(const uint4*)rowp;
      if (lane >= 13 && lane <= 36) qB = *(const uint4*)(rowp + 16);
    }

    // A stage: rows Y..Y+60 (zeros beyond image)
    int RV = 192 - Y;
    for (int m = tid; m < AR * 24; m += 256) {
      int r = m / 24, k = m - r * 24;
      short8 v = (short8)(short)0;
      if (r < RV) v = *(const short8*)(prep + (Y + r) * 192 + k * 8);
      *(short8*)(Al + r * APITCH + k * 16) = v;
    }

    writeB(myB, qA, qB, lane);    // buf 0 (wave-private)
    __syncthreads();              // A region ready

    f32x4 acc[4][7];
#pragma unroll
    for (int mt = 0; mt < 4; mt++)
#pragma unroll
      for (int nt = 0; nt < 7; nt++) acc[mt][nt] = (f32x4)0.f;

    for (int r3 = 0; r3 < 3; r3++) {
      uint4 nA, nB;
      nA.x = nA.y = nA.z = nA.w = 0u; nB.x = nB.y = nB.z = nB.w = 0u;
      if (r3 < 2) {
        const char* rowp = (const char*)(prep + (Y + 4*(r3+1) + w) * 192) + lane * 16 - 224;
        if (lane >= 14 && lane <= 37) nA = *(const uint4*)rowp;
        if (lane >= 13 && lane <= 36) nB = *(const uint4*)(rowp + 16);
      }
      // compute row i = 4*r3 + w from buf r3&1
      {
        const char* pB = myB + (r3 & 1) * RB + LB0;
        int i = 4 * r3 + w;
        int rb[4];
#pragma unroll
        for (int mt = 0; mt < 4; mt++) {
          int ra = i + 16 * mt + c;
          rb[mt] = (ra > 60 ? 60 : ra) * APITCH + 16 * h;
        }
        short8 Wf[8];
#pragma unroll
        for (int wi = 0; wi < 7; wi++) Wf[wi] = *(const short8*)(pB + 32 * wi);
#pragma unroll
        for (int t = 0; t < 6; t++) {
          short8 Af[4];
#pragma unroll
          for (int mt = 0; mt < 4; mt++) Af[mt] = *(const short8*)(Al + rb[mt] + 64 * t);
#pragma unroll
          for (int mt = 0; mt < 4; mt++)
#pragma unroll
            for (int nt = 0; nt < 7; nt++)
              acc[mt][nt] = __builtin_amdgcn_mfma_f32_16x16x32_bf16(Af[mt], Wf[(2*t+6-nt) & 7], acc[mt][nt], 0, 0, 0);
          if (t < 5) {
            Wf[(2*t+7) & 7] = *(const short8*)(pB + 32 * (2*t+7));
            Wf[(2*t+8) & 7] = *(const short8*)(pB + 32 * (2*t+8));
          }
        }
      }
      if (r3 < 2) writeB(myB + ((r3 + 1) & 1) * RB, nA, nB, lane);
    }

    // ---- epilogue: 4-wave K-combine via LDS, then plain partial stores ----
    __syncthreads();
    if (w >= 2) {
      char* rg = lds + (w - 2) * 17408 + lane * ESTR;
#pragma unroll
      for (int mt = 0; mt < 2; mt++)
#pragma unroll
        for (int nt = 0; nt < 7; nt++) *(f32x4*)(rg + (mt*7+nt)*16) = acc[mt][nt];
    }
    __syncthreads();
    if (w < 2) {
      const char* rg = lds + w * 17408 + lane * ESTR;
#pragma unroll
      for (int mt = 0; mt < 2; mt++)
#pragma unroll
        for (int nt = 0; nt < 7; nt++) {
          f32x4 o = *(const f32x4*)(rg + (mt*7+nt)*16);
          acc[mt][nt][0] += o[0]; acc[mt][nt][1] += o[1]; acc[mt][nt][2] += o[2]; acc[mt][nt][3] += o[3];
        }
    }
    __syncthreads();
    if (w >= 2) {
      char* rg = lds + (w - 2) * 17408 + lane * ESTR;
#pragma unroll
      for (int mt = 2; mt < 4; mt++)
#pragma unroll
        for (int nt = 0; nt < 7; nt++) *(f32x4*)(rg + ((mt-2)*7+nt)*16) = acc[mt][nt];
    }
    __syncthreads();
    if (w < 2) {
      const char* rg = lds + w * 17408 + lane * ESTR;
#pragma unroll
      for (int mt = 2; mt < 4; mt++)
#pragma unroll
        for (int nt = 0; nt < 7; nt++) {
          f32x4 o = *(const f32x4*)(rg + ((mt-2)*7+nt)*16);
          acc[mt][nt][0] += o[0]; acc[mt][nt][1] += o[1]; acc[mt][nt][2] += o[2]; acc[mt][nt][3] += o[3];
        }
    }
    __syncthreads();
    if (w == 1) {   // send acc[0..1] to w0's side
      char* rg = lds + lane * ESTR;
#pragma unroll
      for (int mt = 0; mt < 2; mt++)
#pragma unroll
        for (int nt = 0; nt < 7; nt++) *(f32x4*)(rg + (mt*7+nt)*16) = acc[mt][nt];
    }
    if (w == 0) {   // send acc[2..3] to w1's side
      char* rg = lds + 17408 + lane * ESTR;
#pragma unroll
      for (int mt = 2; mt < 4; mt++)
#pragma unroll
        for (int nt = 0; nt < 7; nt++) *(f32x4*)(rg + ((mt-2)*7+nt)*16) = acc[mt][nt];
    }
    __syncthreads();
    float* part = ws + OFF_PARTS + (size_t)unit * SHALF;
    if (w == 0) {
      const char* rg = lds + lane * ESTR;
#pragma unroll
      for (int mt = 0; mt < 2; mt++)
#pragma unroll
        for (int nt = 0; nt < 7; nt++) {
          f32x4 o = *(const f32x4*)(rg + (mt*7+nt)*16);
          int s = 16 * nt + c;
          if (s <= 96) {
#pragma unroll
            for (int r = 0; r < 4; r++) {
              int sy = 16 * mt + 4 * h + r;
              part[sy * 97 + s] = (acc[mt][nt][r] + o[r]) * scale;
            }
          }
        }
    } else if (w == 1) {
      const char* rg = lds + 17408 + lane * ESTR;
#pragma unroll
      for (int mt = 2; mt < 4; mt++)
#pragma unroll
        for (int nt = 0; nt < 7; nt++) {
          f32x4 o = *(const f32x4*)(rg + ((mt-2)*7+nt)*16);
          int s = 16 * nt + c;
          if (s <= 96) {
#pragma unroll
            for (int r = 0; r < 4; r++) {
              int sy = 16 * mt + 4 * h + r;
              if (sy <= 48)
                part[sy * 97 + s] = (acc[mt][nt][r] + o[r]) * scale;
            }
          }
        }
    }
  }
}

// ---------------- Kernel 3: 16-chunk reduce -> Sred + global max ----------------
__global__ __launch_bounds__(256) void reduce_max(float* __restrict__ ws) {
  int blk = blockIdx.x;
  int tj = blk / RSEG, seg = blk - tj * RSEG;
  int t = tj >> 3, jb = tj & 7;
  int imgbase = t * 24 + jb * 3;
  int tid = threadIdx.x;
  __shared__ float wsh[24];
  if (tid < 24) wsh[tid] = (1.f / 3.f) / (ws[OFF_NORM + t * 24 + tid] + EPSF);
  __syncthreads();
  int off = seg * RCHK + tid;
  bool act = (tid < RCHK) && (off < SHALF);
  float p0 = 0.f, p1 = 0.f, p2 = 0.f;
  if (act) {
    const float* P = ws + OFF_PARTS;
    const float* pa = P + (size_t)((imgbase + 0) * 16) * SHALF + off;
    const float* pb = P + (size_t)((imgbase + 1) * 16) * SHALF + off;
    const float* pc = P + (size_t)((imgbase + 2) * 16) * SHALF + off;
#pragma unroll
    for (int ch = 0; ch < 16; ch++) {
      p0 += pa[ch * SHALF]; p1 += pb[ch * SHALF]; p2 += pc[ch * SHALF];
    }
    float* Sred = ws + OFF_SRED;
    Sred[(size_t)(imgbase + 0) * SHALF + off] = p0;
    Sred[(size_t)(imgbase + 1) * SHALF + off] = p1;
    Sred[(size_t)(imgbase + 2) * SHALF + off] = p2;
  }
  float mx = 0.f;
#pragma unroll
  for (int i = 0; i < 8; i++)
    mx = fmaxf(mx, p0 * wsh[i*3] + p1 * wsh[i*3+1] + p2 * wsh[i*3+2]);
#pragma unroll
  for (int o = 32; o > 0; o >>= 1) mx = fmaxf(mx, __shfl_down(mx, o));
  __shared__ float rp[4];
  int lane = tid & 63, wv = tid >> 6;
  if (!lane) rp[wv] = mx;
  __syncthreads();
  if (!tid) {
    mx = fmaxf(fmaxf(rp[0], rp[1]), fmaxf(rp[2], rp[3]));
    atomicMax((int*)ws + OFF_MAX + t, __float_as_int(mx));   // positive floats
  }
}

// ---------------- Kernel 4: loss over Sred + last-block finalize ----------------
__global__ __launch_bounds__(256) void loss_final(float* __restrict__ ws,
                                                  float* __restrict__ out) {
  __shared__ float wsh[48];
  int tid = threadIdx.x;
  if (tid < 48) wsh[tid] = (1.f / 3.f) / (ws[OFF_NORM + tid] + EPSF);
  __syncthreads();
  float imp = 1.f / (__int_as_float(((const int*)ws)[OFF_MAX])     + EPSF);
  float imt = 1.f / (__int_as_float(((const int*)ws)[OFF_MAX + 1]) + EPSF);
  float acc = 0.f;
  const float* Sred = ws + OFF_SRED;
  for (int idx = blockIdx.x * 256 + tid; idx < 8 * SHALF; idx += LOSSB2 * 256) {
    int jb = idx / SHALF, off = idx - jb * SHALF;
    const float* Pp = Sred + (size_t)(3 * jb) * SHALF + off;
    const float* Tt = Sred + (size_t)(24 + 3 * jb) * SHALF + off;
    float p0 = Pp[0], p1 = Pp[SHALF], p2 = Pp[2 * SHALF];
    float q0 = Tt[0], q1 = Tt[SHALF], q2 = Tt[2 * SHALF];
    float a8 = 0.f;
#pragma unroll
    for (int i = 0; i < 8; i++) {
      float pv = (p0 * wsh[i*3] + p1 * wsh[i*3+1] + p2 * wsh[i*3+2]) * imp;
      float tv = (q0 * wsh[24+i*3] + q1 * wsh[24+i*3+1] + q2 * wsh[24+i*3+2]) * imt;
      a8 += fabsf(pv - tv);
    }
    acc += ((off < 97) ? 1.f : 2.f) * a8;   // sy=0 row once, others mirror x2
  }
#pragma unroll
  for (int o = 32; o > 0; o >>= 1) acc += __shfl_down(acc, o);
  __shared__ float r[4];
  int lane = tid & 63, wv = tid >> 6;
  if (!lane) r[wv] = acc;
  __syncthreads();
  if (!tid) {
    float bs = (r[0] + r[1]) + (r[2] + r[3]);
    atomicAdd(&ws[OFF_ACC], bs);
    __threadfence();
    int old = atomicAdd((int*)ws + OFF_CNT3, 1);
    if (old == LOSSB2 - 1) {
      float total = atomicAdd(&ws[OFF_ACC], 0.f);
      out[0] = total * (1.0f / 602176.0f);   // mean over 8*8*97*97
    }
  }
}

extern "C" void kernel_launch(void* const* d_in, const int* in_sizes, int n_in,
                              void* d_out, int out_size, void* d_ws, size_t ws_size,
                              hipStream_t stream) {
  const float* pred   = (const float*)d_in[0];
  const float* target = (const float*)d_in[1];
  float* ws  = (float*)d_ws;
  float* out = (float*)d_out;

  // zero scalars/counters: floats [144, 304)
  hipMemsetAsync((char*)d_ws + 144 * sizeof(float), 0, 160 * sizeof(float), stream);
  hipLaunchKernelGGL(stats_prep,    dim3(192),       dim3(256), 0, stream, pred, target, ws);
  hipLaunchKernelGGL(autocorr_mfma, dim3(512),       dim3(256), 0, stream, ws);
  hipLaunchKernelGGL(reduce_max,    dim3(16 * RSEG), dim3(256), 0, stream, ws);
  hipLaunchKernelGGL(loss_final,    dim3(LOSSB2),    dim3(256), 0, stream, ws, out);
}

// Round 8
// 61.431 us; speedup vs baseline: 2.8023x; 1.1302x over previous
//
#include <hip/hip_runtime.h>
#include <math.h>

#define EPSF 1e-8f
#define HW 36864
#define SHALF 4753           // 49*97 stored upper half per corr map

// ws float offsets
#define OFF_INV    0
#define OFF_NORM   48
#define OFF_MAX    144       // [0]=pred max bits, [1]=target max bits
#define OFF_ACC    146       // loss accumulator
#define OFF_CNT3   148       // loss finalize counter
#define OFF_PART   160       // 48*2 per-image sum/sumsq atomic partials
#define OFF_CTR    256       // 48 per-image arrival counters
#define OFF_PARTS  1024      // 768*4753 floats: per-(img,chunk) partial corr
#define OFF_SRED   3651328   // 48*4753 floats: chunk-reduced corr maps
#define OFF_PREP   3879472   // ushort region: 48*36864 centered-bf16 images

// autocorr geometry
#define CY 12                // rows per unit; 16 chunks/img; 768 blocks = 3/CU, 1 gen
#define AR 61                // staged A rows
#define APITCH 400           // bytes per A row
#define CPB4 736             // bytes per B parity copy (45 chunks x 16B + 16 slack)
#define RBW (4*CPB4)         // 2944 bytes per staged B row (4 copies, shifts 0..3)
#define ABYTES (AR*APITCH)   // 24400
#define BBYTES (4*2*RBW)     // 4 waves x dbuf = 23552
#define LDSB (ABYTES + BBYTES)  // 47952 -> 3 blocks/CU
#define ESTR 240             // epilogue lane stride (60 dw, gcd(28,32)=4 -> uniform)

#define RSEG 19              // reduce_max segments per (t,j)
#define RCHK 251             // offs per segment
#define LOSSB2 38            // loss blocks

typedef short short8 __attribute__((ext_vector_type(8)));
typedef float f32x4 __attribute__((ext_vector_type(4)));

__device__ __forceinline__ unsigned int pk2(float a, float b) {
  union { float f; unsigned int u; } x, y;
  x.f = a; y.f = b;
  unsigned int ra = x.u + 0x7fffu + ((x.u >> 16) & 1u);   // RNE to bf16
  unsigned int rb = y.u + 0x7fffu + ((y.u >> 16) & 1u);
  return (ra >> 16) | (rb & 0xffff0000u);
}

// ---------------- Kernel 1: fused stats + centered-bf16 prep ----------------
__global__ __launch_bounds__(256) void stats_prep(const float* __restrict__ pred,
                                                  const float* __restrict__ target,
                                                  float* __restrict__ ws) {
  int blk = blockIdx.x, tid = threadIdx.x;
  int img = blk >> 2, qtr = blk & 3;
  int t = img / 24, local = img % 24;
  const float* src = (t ? target : pred) + (size_t)local * HW + qtr * 9216;

  const float4* s4 = (const float4*)src;
  float s = 0.f, sq = 0.f;
  for (int i = tid; i < 2304; i += 256) {
    float4 v = s4[i];
    s  += (v.x + v.y) + (v.z + v.w);
    sq += (v.x*v.x + v.y*v.y) + (v.z*v.z + v.w*v.w);
  }
#pragma unroll
  for (int o = 32; o > 0; o >>= 1) { s += __shfl_down(s, o); sq += __shfl_down(sq, o); }
  __shared__ float rs[4], rq[4], bcast[1];
  int lane = tid & 63, wv = tid >> 6;
  if (!lane) { rs[wv] = s; rq[wv] = sq; }
  __syncthreads();
  if (!tid) {
    s  = (rs[0] + rs[1]) + (rs[2] + rs[3]);
    sq = (rq[0] + rq[1]) + (rq[2] + rq[3]);
    atomicAdd(&ws[OFF_PART + 2*img],     s);
    atomicAdd(&ws[OFF_PART + 2*img + 1], sq);
    __threadfence();
    atomicAdd((int*)ws + OFF_CTR + img, 1);
    while (atomicAdd((int*)ws + OFF_CTR + img, 0) < 4) { }
    float S1 = atomicAdd(&ws[OFF_PART + 2*img],     0.f);
    float Q  = atomicAdd(&ws[OFF_PART + 2*img + 1], 0.f);
    float mean = S1 / (float)HW;
    float M2 = fmaxf(Q - S1 * S1 / (float)HW, 0.f);
    float inv = 1.f / (sqrtf(M2 / (float)(HW - 1)) + EPSF);
    bcast[0] = mean;
    if (qtr == 0) {
      ws[OFF_INV  + img] = inv;
      ws[OFF_NORM + img] = sqrtf(M2) * inv;   // sqrt(sum xn^2)
    }
  }
  __syncthreads();
  float mean = bcast[0];
  unsigned short* prep = (unsigned short*)(ws + OFF_PREP) + (size_t)img * HW + qtr * 9216;
  for (int i = tid; i < 2304; i += 256) {
    float4 v = s4[i];
    uint2 d; d.x = pk2(v.x - mean, v.y - mean); d.y = pk2(v.z - mean, v.w - mean);
    *(uint2*)(prep + i * 4) = d;
  }
}

// write one staged B row: 4 parity copies (left-shift by p elems), p = 0..3
__device__ __forceinline__ void writeB4(char* buf, uint4 qA, uint4 qB, int lane) {
  if (lane < 45) {
    unsigned int D[6];
    D[0] = qA.x; D[1] = qA.y; D[2] = qA.z; D[3] = qA.w; D[4] = qB.x; D[5] = qB.y;
    unsigned int Sh[5];
#pragma unroll
    for (int j = 0; j < 5; j++) Sh[j] = (D[j] >> 16) | (D[j+1] << 16);
    char* base = buf + lane * 16;
    uint4 v0; v0.x = D[0];  v0.y = D[1];  v0.z = D[2];  v0.w = D[3];
    uint4 v1; v1.x = Sh[0]; v1.y = Sh[1]; v1.z = Sh[2]; v1.w = Sh[3];
    uint4 v2; v2.x = D[1];  v2.y = D[2];  v2.z = D[3];  v2.w = D[4];
    uint4 v3; v3.x = Sh[1]; v3.y = Sh[2]; v3.z = Sh[3]; v3.w = Sh[4];
    *(uint4*)(base)            = v0;
    *(uint4*)(base + CPB4)     = v1;
    *(uint4*)(base + 2*CPB4)   = v2;
    *(uint4*)(base + 3*CPB4)   = v3;
  }
}

// ---------------- Kernel 2: autocorrelation via bf16 MFMA ----------------
// 768 blocks (img,chunk), 3/CU, one generation. Wave (rw,sh): rw owns rows
// {2k+rw}, sh owns sy-tiles {2sh,2sh+1}. acc[2][7]; wave-private dbuf B rows
// as 4 parity copies (8B-aligned window reads); no barriers in the K loop.
__global__ __launch_bounds__(256, 3) void autocorr_mfma(float* __restrict__ ws) {
  int blk = blockIdx.x;
  int img = blk >> 4, chunk = blk & 15;
  int Y = chunk * CY;
  const unsigned short* prep = (const unsigned short*)(ws + OFF_PREP) + (size_t)img * HW;
  float inv = ws[OFF_INV + img];
  float scale = inv * inv;

  __shared__ __align__(16) char lds[LDSB];
  char* Al = lds;
  char* Bl = lds + ABYTES;

  int tid = threadIdx.x;
  int w = tid >> 6, lane = tid & 63, c = lane & 15, h = lane >> 4;
  int rw = w & 1, sh = w >> 1;

  // lane-constant B window base: p8 = (-c) mod 8, read copy p4 = p8&3
  int p8 = (8 - (c & 7)) & 7;
  int p4 = p8 & 3;
  int q_l = (c == 0) ? 0 : ((c <= 8) ? 1 : 2);
  int LB0 = p4 * CPB4 + 16 * (h - q_l) + 128 + ((p8 & 4) ? 8 : 0);  // +32*wi

  char* myB = Bl + w * (2 * RBW);

  // ---- B row 0 prologue loads (this wave's first row = Y+rw) ----
  uint4 qA, qB;
  qA.x = qA.y = qA.z = qA.w = 0u; qB.x = qB.y = qB.z = qB.w = 0u;
  {
    const char* rowp = (const char*)(prep + (Y + rw) * 192) + lane * 16 - 224;
    if (lane >= 14 && lane <= 37) qA = *(const uint4*)rowp;
    if (lane >= 13 && lane <= 36) qB = *(const uint4*)(rowp + 16);
  }

  // ---- A stage: rows Y..Y+60 (zeros beyond image) ----
  int RV = 192 - Y;
  for (int m = tid; m < AR * 24; m += 256) {
    int r = m / 24, k = m - r * 24;
    short8 v = (short8)(short)0;
    if (r < RV) v = *(const short8*)(prep + (Y + r) * 192 + k * 8);
    *(short8*)(Al + r * APITCH + k * 16) = v;
  }

  writeB4(myB, qA, qB, lane);   // buf 0 (wave-private)
  __syncthreads();              // A region ready

  f32x4 acc[2][7];
#pragma unroll
  for (int mtl = 0; mtl < 2; mtl++)
#pragma unroll
    for (int nt = 0; nt < 7; nt++) acc[mtl][nt] = (f32x4)0.f;

  union WU { uint2 u2[2]; short8 s8; };

#pragma unroll 1
  for (int k = 0; k < 6; k++) {
    // issue next row's global loads (hide under this row's compute)
    uint4 nA, nB;
    nA.x = nA.y = nA.z = nA.w = 0u; nB.x = nB.y = nB.z = nB.w = 0u;
    if (k < 5) {
      const char* rowp = (const char*)(prep + (Y + 2*(k+1) + rw) * 192) + lane * 16 - 224;
      if (lane >= 14 && lane <= 37) nA = *(const uint4*)rowp;
      if (lane >= 13 && lane <= 36) nB = *(const uint4*)(rowp + 16);
    }

    const char* pB = myB + (k & 1) * RBW + LB0;
    int i = 2 * k + rw;
    int rb0, rb1;
    {
      int ra0 = i + 16 * (2 * sh) + c;     // mt = 2sh
      int ra1 = ra0 + 16;                  // mt = 2sh+1
      rb0 = (ra0 > 60 ? 60 : ra0) * APITCH + 16 * h;
      rb1 = (ra1 > 60 ? 60 : ra1) * APITCH + 16 * h;
    }

    short8 Wf[8];
#pragma unroll
    for (int wi = 0; wi < 7; wi++) {
      WU u; u.u2[0] = *(const uint2*)(pB + 32 * wi); u.u2[1] = *(const uint2*)(pB + 32 * wi + 8);
      Wf[wi] = u.s8;
    }
#pragma unroll
    for (int t = 0; t < 6; t++) {
      short8 A0 = *(const short8*)(Al + rb0 + 64 * t);
      short8 A1 = *(const short8*)(Al + rb1 + 64 * t);
      __builtin_amdgcn_s_setprio(1);
#pragma unroll
      for (int nt = 0; nt < 7; nt++)
        acc[0][nt] = __builtin_amdgcn_mfma_f32_16x16x32_bf16(A0, Wf[(2*t+6-nt) & 7], acc[0][nt], 0, 0, 0);
#pragma unroll
      for (int nt = 0; nt < 7; nt++)
        acc[1][nt] = __builtin_amdgcn_mfma_f32_16x16x32_bf16(A1, Wf[(2*t+6-nt) & 7], acc[1][nt], 0, 0, 0);
      __builtin_amdgcn_s_setprio(0);
      if (t < 5) {
        WU ua; ua.u2[0] = *(const uint2*)(pB + 32*(2*t+7)); ua.u2[1] = *(const uint2*)(pB + 32*(2*t+7) + 8);
        Wf[(2*t+7) & 7] = ua.s8;
        WU ub; ub.u2[0] = *(const uint2*)(pB + 32*(2*t+8)); ub.u2[1] = *(const uint2*)(pB + 32*(2*t+8) + 8);
        Wf[(2*t+8) & 7] = ub.s8;
      }
    }
    if (k < 5) writeB4(myB + ((k + 1) & 1) * RBW, nA, nB, lane);
  }

  // ---- epilogue: rw-pair K-combine via LDS, then plain partial stores ----
  __syncthreads();
  if (rw == 1) {
    char* rg = lds + sh * (64 * ESTR) + lane * ESTR;
#pragma unroll
    for (int mtl = 0; mtl < 2; mtl++)
#pragma unroll
      for (int nt = 0; nt < 7; nt++) *(f32x4*)(rg + (mtl*7+nt)*16) = acc[mtl][nt];
  }
  __syncthreads();
  if (rw == 0) {
    const char* rg = lds + sh * (64 * ESTR) + lane * ESTR;
    float* part = ws + OFF_PARTS + (size_t)blk * SHALF;
#pragma unroll
    for (int mtl = 0; mtl < 2; mtl++) {
#pragma unroll
      for (int nt = 0; nt < 7; nt++) {
        f32x4 o = *(const f32x4*)(rg + (mtl*7+nt)*16);
        int s = 16 * nt + c;
        if (s <= 96) {
#pragma unroll
          for (int r = 0; r < 4; r++) {
            int sy = 16 * (2 * sh + mtl) + 4 * h + r;
            if (sy <= 48)
              part[sy * 97 + s] = (acc[mtl][nt][r] + o[r]) * scale;
          }
        }
      }
    }
  }
}

// ---------------- Kernel 3: 16-chunk reduce -> Sred + global max ----------------
__global__ __launch_bounds__(256) void reduce_max(float* __restrict__ ws) {
  int blk = blockIdx.x;
  int tj = blk / RSEG, seg = blk - tj * RSEG;
  int t = tj >> 3, jb = tj & 7;
  int imgbase = t * 24 + jb * 3;
  int tid = threadIdx.x;
  __shared__ float wsh[24];
  if (tid < 24) wsh[tid] = (1.f / 3.f) / (ws[OFF_NORM + t * 24 + tid] + EPSF);
  __syncthreads();
  int off = seg * RCHK + tid;
  bool act = (tid < RCHK) && (off < SHALF);
  float p0 = 0.f, p1 = 0.f, p2 = 0.f;
  if (act) {
    const float* P = ws + OFF_PARTS;
    const float* pa = P + (size_t)((imgbase + 0) * 16) * SHALF + off;
    const float* pb = P + (size_t)((imgbase + 1) * 16) * SHALF + off;
    const float* pc = P + (size_t)((imgbase + 2) * 16) * SHALF + off;
#pragma unroll
    for (int ch = 0; ch < 16; ch++) {
      p0 += pa[ch * SHALF]; p1 += pb[ch * SHALF]; p2 += pc[ch * SHALF];
    }
    float* Sred = ws + OFF_SRED;
    Sred[(size_t)(imgbase + 0) * SHALF + off] = p0;
    Sred[(size_t)(imgbase + 1) * SHALF + off] = p1;
    Sred[(size_t)(imgbase + 2) * SHALF + off] = p2;
  }
  float mx = 0.f;
#pragma unroll
  for (int i = 0; i < 8; i++)
    mx = fmaxf(mx, p0 * wsh[i*3] + p1 * wsh[i*3+1] + p2 * wsh[i*3+2]);
#pragma unroll
  for (int o = 32; o > 0; o >>= 1) mx = fmaxf(mx, __shfl_down(mx, o));
  __shared__ float rp[4];
  int lane = tid & 63, wv = tid >> 6;
  if (!lane) rp[wv] = mx;
  __syncthreads();
  if (!tid) {
    mx = fmaxf(fmaxf(rp[0], rp[1]), fmaxf(rp[2], rp[3]));
    atomicMax((int*)ws + OFF_MAX + t, __float_as_int(mx));   // positive floats
  }
}

// ---------------- Kernel 4: loss over Sred + last-block finalize ----------------
__global__ __launch_bounds__(256) void loss_final(float* __restrict__ ws,
                                                  float* __restrict__ out) {
  __shared__ float wsh[48];
  int tid = threadIdx.x;
  if (tid < 48) wsh[tid] = (1.f / 3.f) / (ws[OFF_NORM + tid] + EPSF);
  __syncthreads();
  float imp = 1.f / (__int_as_float(((const int*)ws)[OFF_MAX])     + EPSF);
  float imt = 1.f / (__int_as_float(((const int*)ws)[OFF_MAX + 1]) + EPSF);
  float acc = 0.f;
  const float* Sred = ws + OFF_SRED;
  for (int idx = blockIdx.x * 256 + tid; idx < 8 * SHALF; idx += LOSSB2 * 256) {
    int jb = idx / SHALF, off = idx - jb * SHALF;
    const float* Pp = Sred + (size_t)(3 * jb) * SHALF + off;
    const float* Tt = Sred + (size_t)(24 + 3 * jb) * SHALF + off;
    float p0 = Pp[0], p1 = Pp[SHALF], p2 = Pp[2 * SHALF];
    float q0 = Tt[0], q1 = Tt[SHALF], q2 = Tt[2 * SHALF];
    float a8 = 0.f;
#pragma unroll
    for (int i = 0; i < 8; i++) {
      float pv = (p0 * wsh[i*3] + p1 * wsh[i*3+1] + p2 * wsh[i*3+2]) * imp;
      float tv = (q0 * wsh[24+i*3] + q1 * wsh[24+i*3+1] + q2 * wsh[24+i*3+2]) * imt;
      a8 += fabsf(pv - tv);
    }
    acc += ((off < 97) ? 1.f : 2.f) * a8;   // sy=0 row once, others mirror x2
  }
#pragma unroll
  for (int o = 32; o > 0; o >>= 1) acc += __shfl_down(acc, o);
  __shared__ float r[4];
  int lane = tid & 63, wv = tid >> 6;
  if (!lane) r[wv] = acc;
  __syncthreads();
  if (!tid) {
    float bs = (r[0] + r[1]) + (r[2] + r[3]);
    atomicAdd(&ws[OFF_ACC], bs);
    __threadfence();
    int old = atomicAdd((int*)ws + OFF_CNT3, 1);
    if (old == LOSSB2 - 1) {
      float total = atomicAdd(&ws[OFF_ACC], 0.f);
      out[0] = total * (1.0f / 602176.0f);   // mean over 8*8*97*97
    }
  }
}

extern "C" void kernel_launch(void* const* d_in, const int* in_sizes, int n_in,
                              void* d_out, int out_size, void* d_ws, size_t ws_size,
                              hipStream_t stream) {
  const float* pred   = (const float*)d_in[0];
  const float* target = (const float*)d_in[1];
  float* ws  = (float*)d_ws;
  float* out = (float*)d_out;

  // zero scalars/counters: floats [144, 304)
  hipMemsetAsync((char*)d_ws + 144 * sizeof(float), 0, 160 * sizeof(float), stream);
  hipLaunchKernelGGL(stats_prep,    dim3(192),       dim3(256), 0, stream, pred, target, ws);
  hipLaunchKernelGGL(autocorr_mfma, dim3(768),       dim3(256), 0, stream, ws);
  hipLaunchKernelGGL(reduce_max,    dim3(16 * RSEG), dim3(256), 0, stream, ws);
  hipLaunchKernelGGL(loss_final,    dim3(LOSSB2),    dim3(256), 0, stream, ws, out);
}